// Round 1
// baseline (447.758 us; speedup 1.0000x reference)
//
#include <hip/hip_runtime.h>
#include <hip/hip_bf16.h>

// ---------------------------------------------------------------------------
// MultiHeadAttention_21887153340754
// N=4096, IN=1000(pad 1024), H1=2048, H2=1024, EMB=512, HEADS=8, depth=64, OUT=1000
//
// Math: attention here is LINEAR in scores (no softmax):
//   att = (qh @ M / sqrt(d)) / denom,  M = kh^T @ vh  (per head, 64x64)
//   denom = (qh . ksum)/sqrt(d) + 1e-8, ksum = colsum(kh)
// => never materialize the 4096x4096 score matrix.
// ---------------------------------------------------------------------------

typedef __attribute__((ext_vector_type(4))) float f32x4;
typedef __attribute__((ext_vector_type(8))) short bf16x8;

// ---- workspace layout (bytes) ---------------------------------------------
static constexpr size_t OFF_XB   = 0;                      // bf16 [4096][1024]
static constexpr size_t OFF_WT1  = OFF_XB   + 8388608;     // bf16 [6144][1024]
static constexpr size_t OFF_WT2  = OFF_WT1  + 12582912;    // bf16 [3][1024][2048]
static constexpr size_t OFF_WT3  = OFF_WT2  + 12582912;    // bf16 [3][512][1024]
static constexpr size_t OFF_WTO  = OFF_WT3  + 3145728;     // bf16 [1024][512]
static constexpr size_t OFF_B1C  = OFF_WTO  + 1048576;     // f32  [6144]
static constexpr size_t OFF_H1   = OFF_B1C  + 24576;       // bf16 [4096][6144]
static constexpr size_t OFF_H2   = OFF_H1   + 50331648;    // bf16 [4096][3072]
static constexpr size_t OFF_QKV  = OFF_H2   + 25165824;    // bf16 [4096][1536]
static constexpr size_t OFF_MP   = OFF_QKV  + 12582912;    // f32  [32][8][4160]
static constexpr size_t OFF_MF   = OFF_MP   + 4259840;     // f32  [8][4160]
static constexpr size_t OFF_ATT  = OFF_MF   + 133120;      // bf16 [4096][512]
// total ~134.4 MB

__device__ __forceinline__ void gload16(const __hip_bfloat16* g, __hip_bfloat16* l) {
  __builtin_amdgcn_global_load_lds(
      (const __attribute__((address_space(1))) void*)g,
      (__attribute__((address_space(3))) void*)l, 16, 0, 0);
}

// ---- batch fp32 [4096][1000] -> bf16 [4096][1024] (zero pad) --------------
__global__ void conv_pad_batch(const float* __restrict__ in, __hip_bfloat16* __restrict__ out) {
  int idx = blockIdx.x * 256 + threadIdx.x;          // 4096*1024 total
  int r = idx >> 10, c = idx & 1023;
  float v = (c < 1000) ? in[(size_t)r * 1000 + c] : 0.f;
  out[idx] = __float2bfloat16(v);
}

// ---- concat the 3 b1 biases into [6144] -----------------------------------
__global__ void concat3(const float* __restrict__ a, const float* __restrict__ b,
                        const float* __restrict__ c, float* __restrict__ out) {
  int i = blockIdx.x * 256 + threadIdx.x;
  if (i < 6144) {
    const float* src = (i < 2048) ? a : ((i < 4096) ? b : c);
    out[i] = src[i & 2047];
  }
}

// ---- W [K][N] fp32 -> Wt [Npad][Kpad] bf16 (transpose + pad) --------------
__global__ void transpose_conv(const float* __restrict__ in, __hip_bfloat16* __restrict__ out,
                               int K, int N, int Kpad) {
  __shared__ float tile[32][33];
  int kb = blockIdx.x * 32, nb = blockIdx.y * 32;
  int tx = threadIdx.x, ty = threadIdx.y;            // block (32,8)
  for (int i = ty; i < 32; i += 8) {
    int k = kb + i, n = nb + tx;
    tile[i][tx] = (k < K && n < N) ? in[(size_t)k * N + n] : 0.f;
  }
  __syncthreads();
  for (int i = ty; i < 32; i += 8) {
    int n = nb + i, kp = kb + tx;
    out[(size_t)n * Kpad + kp] = __float2bfloat16(tile[tx][i]);
  }
}

// ---- bf16 MFMA GEMM, m97 structure: 128x128 tile, BK=32, 4 waves ----------
// C[m][n] = sum_k A[m][k] * B[n][k] + bias[n]    (B pre-transposed [N][K])
// EPI: 0 = bf16 store, 1 = bf16 store + relu, 2 = f32 store guarded col<nlimit
template <int EPI>
__global__ __launch_bounds__(256) void gemm_bt(
    const __hip_bfloat16* __restrict__ A, int lda,
    const __hip_bfloat16* __restrict__ B, int ldb,
    const float* __restrict__ bias,
    void* __restrict__ Cout, int ldc, int nlimit, int K) {
  __shared__ __hip_bfloat16 As[128 * 32];
  __shared__ __hip_bfloat16 Bs[128 * 32];
  const int t = threadIdx.x;
  const int m0 = blockIdx.y * 128;
  const int n0 = blockIdx.x * 128;
  const int w = t >> 6, l = t & 63;
  const int wm = (w >> 1) * 64, wn = (w & 1) * 64;   // 2x2 wave grid, 64x64 each
  const int fr = l & 15, fq = l >> 4;
  const int sr = t >> 2, sc = (t & 3) * 8;           // staging: row, col(elem)

  f32x4 acc[4][4] = {};

  const __hip_bfloat16* ga = A + (size_t)(m0 + sr) * lda + sc;
  const __hip_bfloat16* gb = B + (size_t)(n0 + sr) * ldb + sc;
  __hip_bfloat16* la = As + w * 512;                 // wave-uniform LDS dest
  __hip_bfloat16* lb = Bs + w * 512;

  for (int k0 = 0; k0 < K; k0 += 32) {
    gload16(ga, la);
    gload16(ga + (size_t)64 * lda, la + 2048);
    gload16(gb, lb);
    gload16(gb + (size_t)64 * ldb, lb + 2048);
    ga += 32; gb += 32;
    __syncthreads();                                 // drains vmcnt
    bf16x8 af[4], bfr[4];
#pragma unroll
    for (int i = 0; i < 4; ++i) {
      af[i]  = *reinterpret_cast<const bf16x8*>(&As[(wm + i * 16 + fr) * 32 + fq * 8]);
      bfr[i] = *reinterpret_cast<const bf16x8*>(&Bs[(wn + i * 16 + fr) * 32 + fq * 8]);
    }
#pragma unroll
    for (int i = 0; i < 4; ++i)
#pragma unroll
      for (int j = 0; j < 4; ++j)
        acc[i][j] = __builtin_amdgcn_mfma_f32_16x16x32_bf16(af[i], bfr[j], acc[i][j], 0, 0, 0);
    __syncthreads();
  }

  float bv[4];
#pragma unroll
  for (int j = 0; j < 4; ++j) {
    int col = n0 + wn + j * 16 + fr;
    bv[j] = (col < nlimit) ? bias[col] : 0.f;
  }
#pragma unroll
  for (int i = 0; i < 4; ++i) {
#pragma unroll
    for (int j = 0; j < 4; ++j) {
      int col = n0 + wn + j * 16 + fr;
#pragma unroll
      for (int r = 0; r < 4; ++r) {
        int row = m0 + wm + i * 16 + fq * 4 + r;
        float v = acc[i][j][r] + bv[j];
        if (EPI == 1) v = fmaxf(v, 0.f);
        if (EPI <= 1) {
          ((__hip_bfloat16*)Cout)[(size_t)row * ldc + col] = __float2bfloat16(v);
        } else {
          if (col < nlimit) ((float*)Cout)[(size_t)row * ldc + col] = v;
        }
      }
    }
  }
}

// ---- per-head partial M = kh^T vh (64x64) and ksum, over 128-row chunks ---
__global__ __launch_bounds__(256) void kv_outer(const __hip_bfloat16* __restrict__ QKV, int ld,
                                                float* __restrict__ part) {
  __shared__ __hip_bfloat16 kt[128][64];
  __shared__ __hip_bfloat16 vt[128][64];
  const int t = threadIdx.x;
  const int n0 = blockIdx.x * 128;                   // chunk
  const int h = blockIdx.y;                          // head
#pragma unroll
  for (int it = 0; it < 4; ++it) {
    int r = it * 32 + (t >> 3);
    int c = (t & 7) * 8;
    const __hip_bfloat16* kr = &QKV[(size_t)(n0 + r) * ld + 512 + h * 64 + c];
    const __hip_bfloat16* vr = &QKV[(size_t)(n0 + r) * ld + 1024 + h * 64 + c];
    *reinterpret_cast<bf16x8*>(&kt[r][c]) = *reinterpret_cast<const bf16x8*>(kr);
    *reinterpret_cast<bf16x8*>(&vt[r][c]) = *reinterpret_cast<const bf16x8*>(vr);
  }
  __syncthreads();
  const int i = t >> 2, j0 = (t & 3) << 4;
  float acc[16] = {};
  float ks = 0.f;
  for (int r = 0; r < 128; ++r) {
    float kv = __bfloat162float(kt[r][i]);
    ks += kv;
#pragma unroll
    for (int jj = 0; jj < 16; ++jj)
      acc[jj] += kv * __bfloat162float(vt[r][j0 + jj]);
  }
  float* dst = part + ((size_t)blockIdx.x * 8 + h) * 4160;
#pragma unroll
  for (int jj = 0; jj < 16; ++jj) dst[i * 64 + j0 + jj] = acc[jj];
  if ((t & 3) == 0) dst[4096 + i] = ks;
}

// ---- reduce 32 partials -> Mfin [8][4160] (M then ksum) -------------------
__global__ void reduce_m(const float* __restrict__ part, float* __restrict__ Mfin) {
  int h = blockIdx.x, t = threadIdx.x;
  for (int idx = t; idx < 4160; idx += 256) {
    float s = 0.f;
    for (int c = 0; c < 32; ++c) s += part[((size_t)c * 8 + h) * 4160 + idx];
    Mfin[(size_t)h * 4160 + idx] = s;
  }
}

// ---- att[n][h*64+j] = (qh.M[:,j]/8) / ((qh.ksum)/8 + 1e-8) ----------------
__global__ __launch_bounds__(256) void att_kernel(const __hip_bfloat16* __restrict__ QKV, int ld,
                                                  const float* __restrict__ Mfin,
                                                  __hip_bfloat16* __restrict__ att) {
  __shared__ float q[8][512];
  __shared__ float den[8][8];
  const int t = threadIdx.x;
  const int n0 = blockIdx.x * 8;
  for (int e = t; e < 8 * 512; e += 256) {
    int r = e >> 9, c = e & 511;
    q[r][c] = __bfloat162float(QKV[(size_t)(n0 + r) * ld + c]);   // relu'd Q
  }
  __syncthreads();
  if (t < 64) {
    int r = t >> 3, h = t & 7;
    const float* ks = Mfin + (size_t)h * 4160 + 4096;
    float s = 0.f;
    for (int i = 0; i < 64; ++i) s += q[r][h * 64 + i] * ks[i];
    den[r][h] = s * 0.125f + 1e-8f;
  }
  __syncthreads();
  for (int cc = 0; cc < 2; ++cc) {
    int j = t + cc * 256;
    int h = j >> 6, jh = j & 63;
    const float* Mc = Mfin + (size_t)h * 4160;
    float a0[8] = {};
    for (int i = 0; i < 64; ++i) {
      float m = Mc[i * 64 + jh];
#pragma unroll
      for (int r = 0; r < 8; ++r) a0[r] += q[r][h * 64 + i] * m;
    }
#pragma unroll
    for (int r = 0; r < 8; ++r)
      att[(size_t)(n0 + r) * 512 + j] = __float2bfloat16(a0[r] * 0.125f / den[r][h]);
  }
}

// ---------------------------------------------------------------------------
extern "C" void kernel_launch(void* const* d_in, const int* in_sizes, int n_in,
                              void* d_out, int out_size, void* d_ws, size_t ws_size,
                              hipStream_t stream) {
  const float* batch = (const float*)d_in[0];
  const float* w1[3] = {(const float*)d_in[1],  (const float*)d_in[7],  (const float*)d_in[13]};
  const float* b1[3] = {(const float*)d_in[2],  (const float*)d_in[8],  (const float*)d_in[14]};
  const float* w2[3] = {(const float*)d_in[3],  (const float*)d_in[9],  (const float*)d_in[15]};
  const float* b2[3] = {(const float*)d_in[4],  (const float*)d_in[10], (const float*)d_in[16]};
  const float* w3[3] = {(const float*)d_in[5],  (const float*)d_in[11], (const float*)d_in[17]};
  const float* b3[3] = {(const float*)d_in[6],  (const float*)d_in[12], (const float*)d_in[18]};
  const float* wow   = (const float*)d_in[19];
  const float* wob   = (const float*)d_in[20];

  char* ws = (char*)d_ws;
  __hip_bfloat16* XB  = (__hip_bfloat16*)(ws + OFF_XB);
  __hip_bfloat16* WT1 = (__hip_bfloat16*)(ws + OFF_WT1);
  __hip_bfloat16* WT2 = (__hip_bfloat16*)(ws + OFF_WT2);
  __hip_bfloat16* WT3 = (__hip_bfloat16*)(ws + OFF_WT3);
  __hip_bfloat16* WTO = (__hip_bfloat16*)(ws + OFF_WTO);
  float*          B1C = (float*)(ws + OFF_B1C);
  __hip_bfloat16* H1  = (__hip_bfloat16*)(ws + OFF_H1);
  __hip_bfloat16* H2  = (__hip_bfloat16*)(ws + OFF_H2);
  __hip_bfloat16* QKV = (__hip_bfloat16*)(ws + OFF_QKV);
  float*          MP  = (float*)(ws + OFF_MP);
  float*          MF  = (float*)(ws + OFF_MF);
  __hip_bfloat16* ATT = (__hip_bfloat16*)(ws + OFF_ATT);
  float*          OUT = (float*)d_out;

  // 1) input conversion / weight transposition
  conv_pad_batch<<<16384, 256, 0, stream>>>(batch, XB);
  concat3<<<24, 256, 0, stream>>>(b1[0], b1[1], b1[2], B1C);
  for (int p = 0; p < 3; ++p) {
    transpose_conv<<<dim3(32, 64), dim3(32, 8), 0, stream>>>(w1[p], WT1 + (size_t)p * 2048 * 1024, 1000, 2048, 1024);
    transpose_conv<<<dim3(64, 32), dim3(32, 8), 0, stream>>>(w2[p], WT2 + (size_t)p * 1024 * 2048, 2048, 1024, 2048);
    transpose_conv<<<dim3(32, 16), dim3(32, 8), 0, stream>>>(w3[p], WT3 + (size_t)p * 512 * 1024, 1024, 512, 1024);
  }
  transpose_conv<<<dim3(16, 32), dim3(32, 8), 0, stream>>>(wow, WTO, 512, 1000, 512);

  // 2) MLPs
  // G1 (merged q|k|v): [4096,1024] @ [1024,6144] -> H1 (relu, bf16)
  gemm_bt<1><<<dim3(48, 32), 256, 0, stream>>>(XB, 1024, WT1, 1024, B1C, H1, 6144, 6144, 1024);
  // G2 per p: [4096,2048] @ [2048,1024] -> H2 (relu, bf16)
  for (int p = 0; p < 3; ++p)
    gemm_bt<1><<<dim3(8, 32), 256, 0, stream>>>(H1 + (size_t)p * 2048, 6144,
                                                WT2 + (size_t)p * 1024 * 2048, 2048,
                                                b2[p], H2 + (size_t)p * 1024, 3072, 1024, 2048);
  // G3 per p: [4096,1024] @ [1024,512] -> QKV (q,k relu'd; v plain)
  for (int p = 0; p < 2; ++p)
    gemm_bt<1><<<dim3(4, 32), 256, 0, stream>>>(H2 + (size_t)p * 1024, 3072,
                                                WT3 + (size_t)p * 512 * 1024, 1024,
                                                b3[p], QKV + (size_t)p * 512, 1536, 512, 1024);
  gemm_bt<0><<<dim3(4, 32), 256, 0, stream>>>(H2 + (size_t)2 * 1024, 3072,
                                              WT3 + (size_t)2 * 512 * 1024, 1024,
                                              b3[2], QKV + (size_t)2 * 512, 1536, 512, 1024);

  // 3) attention (linear normalization => tiny per-head reductions)
  kv_outer<<<dim3(32, 8), 256, 0, stream>>>(QKV, 1536, MP);
  reduce_m<<<8, 256, 0, stream>>>(MP, MF);
  att_kernel<<<512, 256, 0, stream>>>(QKV, 1536, MF, ATT);

  // 4) output projection: [4096,512] @ [512,1000(+pad)] -> d_out fp32
  gemm_bt<2><<<dim3(8, 32), 256, 0, stream>>>(ATT, 512, WTO, 512, wob, OUT, 1000, 1000, 512);

  (void)in_sizes; (void)n_in; (void)out_size; (void)ws_size;
}

// Round 2
// 287.203 us; speedup vs baseline: 1.5590x; 1.5590x over previous
//
#include <hip/hip_runtime.h>
#include <hip/hip_bf16.h>

// ---------------------------------------------------------------------------
// MultiHeadAttention_21887153340754
// N=4096, IN=1000(pad 1024), H1=2048, H2=1024, EMB=512, HEADS=8, depth=64, OUT=1000
//
// Attention is LINEAR in scores (no softmax):
//   att = (qh @ M / sqrt(d)) / denom,  M = kh^T @ vh (per head, 64x64)
//   denom = (qh . ksum)/sqrt(d) + 1e-8
// => never materialize the 4096x4096 score matrix.
//
// Round 2: big GEMMs (G1,G2) -> 256x256 tile, BK=32, 4-buf LDS ring,
// counted vmcnt(8) pipeline (T4), both-sides XOR chunk swizzle (T2),
// setprio around MFMA cluster (T5). G3/out stay on generalized 128^2 kernel.
// ---------------------------------------------------------------------------

typedef __attribute__((ext_vector_type(4))) float f32x4;
typedef __attribute__((ext_vector_type(8))) short bf16x8;

// ---- workspace layout (bytes) ---------------------------------------------
static constexpr size_t OFF_XB   = 0;                      // bf16 [4096][1024]
static constexpr size_t OFF_WT1  = OFF_XB   + 8388608;     // bf16 [6144][1024]
static constexpr size_t OFF_WT2  = OFF_WT1  + 12582912;    // bf16 [3][1024][2048]
static constexpr size_t OFF_WT3  = OFF_WT2  + 12582912;    // bf16 [3][512][1024]
static constexpr size_t OFF_WTO  = OFF_WT3  + 3145728;     // bf16 [1024][512]
static constexpr size_t OFF_B1C  = OFF_WTO  + 1048576;     // f32  [6144]
static constexpr size_t OFF_H1   = OFF_B1C  + 24576;       // bf16 [4096][6144]
static constexpr size_t OFF_H2   = OFF_H1   + 50331648;    // bf16 [4096][3072]
static constexpr size_t OFF_QKV  = OFF_H2   + 25165824;    // bf16 [4096][1536]
static constexpr size_t OFF_MP   = OFF_QKV  + 12582912;    // f32  [32][8][4160]
static constexpr size_t OFF_MF   = OFF_MP   + 4259840;     // f32  [8][4160]
static constexpr size_t OFF_ATT  = OFF_MF   + 133120;      // bf16 [4096][512]

__device__ __forceinline__ void gload16(const __hip_bfloat16* g, __hip_bfloat16* l) {
  __builtin_amdgcn_global_load_lds(
      (const __attribute__((address_space(1))) void*)g,
      (__attribute__((address_space(3))) void*)l, 16, 0, 0);
}

// ---- batch fp32 [4096][1000] -> bf16 [4096][1024] (zero pad) --------------
__global__ void conv_pad_batch(const float* __restrict__ in, __hip_bfloat16* __restrict__ out) {
  int idx = blockIdx.x * 256 + threadIdx.x;
  int r = idx >> 10, c = idx & 1023;
  float v = (c < 1000) ? in[(size_t)r * 1000 + c] : 0.f;
  out[idx] = __float2bfloat16(v);
}

__global__ void concat3(const float* __restrict__ a, const float* __restrict__ b,
                        const float* __restrict__ c, float* __restrict__ out) {
  int i = blockIdx.x * 256 + threadIdx.x;
  if (i < 6144) {
    const float* src = (i < 2048) ? a : ((i < 4096) ? b : c);
    out[i] = src[i & 2047];
  }
}

// ---- W [K][N] fp32 -> Wt [Npad][Kpad] bf16, batched over z ----------------
__global__ void transpose_conv3(const float* __restrict__ s0, const float* __restrict__ s1,
                                const float* __restrict__ s2, __hip_bfloat16* __restrict__ outb,
                                size_t ostride, int K, int N, int Kpad) {
  const float* in = (blockIdx.z == 0) ? s0 : ((blockIdx.z == 1) ? s1 : s2);
  __hip_bfloat16* out = outb + (size_t)blockIdx.z * ostride;
  __shared__ float tile[32][33];
  int kb = blockIdx.x * 32, nb = blockIdx.y * 32;
  int tx = threadIdx.x, ty = threadIdx.y;            // block (32,8)
  for (int i = ty; i < 32; i += 8) {
    int k = kb + i, n = nb + tx;
    tile[i][tx] = (k < K && n < N) ? in[(size_t)k * N + n] : 0.f;
  }
  __syncthreads();
  for (int i = ty; i < 32; i += 8) {
    int n = nb + i, kp = kb + tx;
    out[(size_t)n * Kpad + kp] = __float2bfloat16(tile[tx][i]);
  }
}

// ---------------------------------------------------------------------------
// gemm_p: 256x256 tile, BK=32, 8 waves (2M x 4N), per-wave 128x64.
// LDS ring of 4 K-tile buffers (A+B = 32KB each, 128KB total).
// Counted vmcnt pipeline: stage tile t+3 while computing tile t; one raw
// s_barrier per K-tile; vmcnt(8) steady, 4/0 at tail.
// Chunk swizzle (both sides): 16B chunk for logical (row r, slot s in 0..3):
//   rho=r>>1, p=(r&1)*4+s, chunk = rho*8 + (p ^ (rho&7))
// => ds_read_b128 fragment reads land 8 lanes per 4-bank group (BW floor).
// ---------------------------------------------------------------------------
__global__ __launch_bounds__(512, 2) void gemm_p(
    const __hip_bfloat16* __restrict__ A, int lda, size_t Az,
    const __hip_bfloat16* __restrict__ B, int ldb, size_t Bz,
    const float* __restrict__ bias0, const float* __restrict__ bias1,
    const float* __restrict__ bias2,
    __hip_bfloat16* __restrict__ Cout, int ldc, size_t Cz,
    int K, int relu) {
  __shared__ __hip_bfloat16 sm[4][2][8192];          // [buf][A/B][256*32]

  const int t = threadIdx.x;
  const int z = blockIdx.z;
  const int m0 = blockIdx.y * 256;
  const int n0 = blockIdx.x * 256;
  A += (size_t)z * Az;
  B += (size_t)z * Bz;
  const float* bias = (z == 0) ? bias0 : ((z == 1) ? bias1 : bias2);

  const int w = t >> 6, l = t & 63;
  const int wm = (w >> 2) * 128;                     // 2 waves in M
  const int wn = (w & 3) * 64;                       // 4 waves in N
  const int fr = l & 15, fq = l >> 4;

  // --- staging source (inverse swizzle): thread t owns chunks t and t+512 ---
  {
  }
  const int rho = t >> 3;
  const int p_st = (t & 7) ^ (rho & 7);
  const int r_st = rho * 2 + (p_st >> 2);            // 0..127
  const int s_st = (p_st & 3) * 8;                   // element col within BK
  const __hip_bfloat16* srcA0 = A + (size_t)(m0 + r_st) * lda + s_st;
  const __hip_bfloat16* srcB0 = B + (size_t)(n0 + r_st) * ldb + s_st;

  // --- swizzled ds_read lane offset (elements) ---
  const int p_ld = ((fr & 1) << 2) | fq;
  const int lane_sw = (fr >> 1) * 64 + ((p_ld ^ (fr >> 1)) << 3);
  const int wm32 = wm * 32, wn32 = wn * 32;

  f32x4 acc[8][4] = {};

  const int NT = K >> 5;

#define STAGE_P(BUF, KT) do {                                                  \
    const __hip_bfloat16* a_ = srcA0 + (size_t)(KT) * 32;                      \
    const __hip_bfloat16* b_ = srcB0 + (size_t)(KT) * 32;                      \
    __hip_bfloat16* lA_ = &sm[(BUF)][0][w * 512];                              \
    __hip_bfloat16* lB_ = &sm[(BUF)][1][w * 512];                              \
    gload16(a_, lA_);                                                          \
    gload16(a_ + (size_t)128 * lda, lA_ + 4096);                               \
    gload16(b_, lB_);                                                          \
    gload16(b_ + (size_t)128 * ldb, lB_ + 4096);                               \
  } while (0)

#define BODY_P(TT, VMSTR) do {                                                 \
    asm volatile("s_waitcnt vmcnt(" VMSTR ")" ::: "memory");                   \
    __builtin_amdgcn_s_barrier();                                              \
    __builtin_amdgcn_sched_barrier(0);                                         \
    const int t_ = (TT);                                                       \
    if (t_ + 3 < NT) { STAGE_P((t_ + 3) & 3, t_ + 3); }                        \
    const __hip_bfloat16* As_ = &sm[t_ & 3][0][0];                             \
    const __hip_bfloat16* Bs_ = &sm[t_ & 3][1][0];                             \
    bf16x8 af[8], bfv[4];                                                      \
    _Pragma("unroll")                                                          \
    for (int i = 0; i < 8; ++i)                                                \
      af[i] = *reinterpret_cast<const bf16x8*>(&As_[wm32 + i * 512 + lane_sw]);\
    _Pragma("unroll")                                                          \
    for (int j = 0; j < 4; ++j)                                                \
      bfv[j] = *reinterpret_cast<const bf16x8*>(&Bs_[wn32 + j * 512 + lane_sw]);\
    __builtin_amdgcn_s_setprio(1);                                             \
    _Pragma("unroll")                                                          \
    for (int i = 0; i < 8; ++i)                                                \
      _Pragma("unroll")                                                        \
      for (int j = 0; j < 4; ++j)                                              \
        acc[i][j] = __builtin_amdgcn_mfma_f32_16x16x32_bf16(af[i], bfv[j],     \
                                                            acc[i][j], 0, 0, 0);\
    __builtin_amdgcn_s_setprio(0);                                             \
  } while (0)

  // prologue: 3 tiles in flight
  STAGE_P(0, 0);
  STAGE_P(1, 1);
  STAGE_P(2, 2);

  for (int tt = 0; tt < NT - 2; ++tt) BODY_P(tt, "8");
  BODY_P(NT - 2, "4");
  BODY_P(NT - 1, "0");

#undef STAGE_P
#undef BODY_P

  // epilogue
  float bv[4];
#pragma unroll
  for (int j = 0; j < 4; ++j) bv[j] = bias[n0 + wn + j * 16 + fr];
  __hip_bfloat16* C = Cout + (size_t)z * Cz;
#pragma unroll
  for (int i = 0; i < 8; ++i) {
#pragma unroll
    for (int j = 0; j < 4; ++j) {
      const int col = n0 + wn + j * 16 + fr;
#pragma unroll
      for (int r = 0; r < 4; ++r) {
        const int row = m0 + wm + i * 16 + fq * 4 + r;
        float v = acc[i][j][r] + bv[j];
        if (relu) v = fmaxf(v, 0.f);
        C[(size_t)row * ldc + col] = __float2bfloat16(v);
      }
    }
  }
}

// ---- generalized 128^2 m97-style GEMM (small shapes: G3, out-proj) --------
// epi: 0 = bf16, 1 = bf16+relu, 2 = f32 store guarded col<nlimit,
//      3 = bf16 + relu iff z<2
__global__ __launch_bounds__(256) void gemm_bt(
    const __hip_bfloat16* __restrict__ A, int lda, size_t Az,
    const __hip_bfloat16* __restrict__ B, int ldb, size_t Bz,
    const float* __restrict__ bias0, const float* __restrict__ bias1,
    const float* __restrict__ bias2,
    void* __restrict__ Cout, int ldc, size_t Cz,
    int nlimit, int K, int epi) {
  __shared__ __hip_bfloat16 As[128 * 32];
  __shared__ __hip_bfloat16 Bs[128 * 32];
  const int t = threadIdx.x;
  const int z = blockIdx.z;
  const int m0 = blockIdx.y * 128;
  const int n0 = blockIdx.x * 128;
  A += (size_t)z * Az;
  B += (size_t)z * Bz;
  const float* bias = (z == 0) ? bias0 : ((z == 1) ? bias1 : bias2);
  const int w = t >> 6, l = t & 63;
  const int wm = (w >> 1) * 64, wn = (w & 1) * 64;
  const int fr = l & 15, fq = l >> 4;
  const int sr = t >> 2, sc = (t & 3) * 8;

  f32x4 acc[4][4] = {};

  const __hip_bfloat16* ga = A + (size_t)(m0 + sr) * lda + sc;
  const __hip_bfloat16* gb = B + (size_t)(n0 + sr) * ldb + sc;
  __hip_bfloat16* la = As + w * 512;
  __hip_bfloat16* lb = Bs + w * 512;

  for (int k0 = 0; k0 < K; k0 += 32) {
    gload16(ga, la);
    gload16(ga + (size_t)64 * lda, la + 2048);
    gload16(gb, lb);
    gload16(gb + (size_t)64 * ldb, lb + 2048);
    ga += 32; gb += 32;
    __syncthreads();
    bf16x8 af[4], bfr[4];
#pragma unroll
    for (int i = 0; i < 4; ++i) {
      af[i]  = *reinterpret_cast<const bf16x8*>(&As[(wm + i * 16 + fr) * 32 + fq * 8]);
      bfr[i] = *reinterpret_cast<const bf16x8*>(&Bs[(wn + i * 16 + fr) * 32 + fq * 8]);
    }
#pragma unroll
    for (int i = 0; i < 4; ++i)
#pragma unroll
      for (int j = 0; j < 4; ++j)
        acc[i][j] = __builtin_amdgcn_mfma_f32_16x16x32_bf16(af[i], bfr[j], acc[i][j], 0, 0, 0);
    __syncthreads();
  }

  const bool dorelu = (epi == 1) || (epi == 3 && z < 2);
  float bv[4];
#pragma unroll
  for (int j = 0; j < 4; ++j) {
    int col = n0 + wn + j * 16 + fr;
    bv[j] = (col < nlimit) ? bias[col] : 0.f;
  }
#pragma unroll
  for (int i = 0; i < 4; ++i) {
#pragma unroll
    for (int j = 0; j < 4; ++j) {
      int col = n0 + wn + j * 16 + fr;
#pragma unroll
      for (int r = 0; r < 4; ++r) {
        int row = m0 + wm + i * 16 + fq * 4 + r;
        float v = acc[i][j][r] + bv[j];
        if (dorelu) v = fmaxf(v, 0.f);
        if (epi == 2) {
          if (col < nlimit)
            ((float*)Cout)[(size_t)row * ldc + col] = v;
        } else {
          ((__hip_bfloat16*)Cout + (size_t)z * Cz)[(size_t)row * ldc + col] = __float2bfloat16(v);
        }
      }
    }
  }
}

// ---- per-head partial M = kh^T vh (64x64) and ksum, over 128-row chunks ---
__global__ __launch_bounds__(256) void kv_outer(const __hip_bfloat16* __restrict__ QKV, int ld,
                                                float* __restrict__ part) {
  __shared__ __hip_bfloat16 kt[128][64];
  __shared__ __hip_bfloat16 vt[128][64];
  const int t = threadIdx.x;
  const int n0 = blockIdx.x * 128;
  const int h = blockIdx.y;
#pragma unroll
  for (int it = 0; it < 4; ++it) {
    int r = it * 32 + (t >> 3);
    int c = (t & 7) * 8;
    const __hip_bfloat16* kr = &QKV[(size_t)(n0 + r) * ld + 512 + h * 64 + c];
    const __hip_bfloat16* vr = &QKV[(size_t)(n0 + r) * ld + 1024 + h * 64 + c];
    *reinterpret_cast<bf16x8*>(&kt[r][c]) = *reinterpret_cast<const bf16x8*>(kr);
    *reinterpret_cast<bf16x8*>(&vt[r][c]) = *reinterpret_cast<const bf16x8*>(vr);
  }
  __syncthreads();
  const int i = t >> 2, j0 = (t & 3) << 4;
  float acc[16] = {};
  float ks = 0.f;
  for (int r = 0; r < 128; ++r) {
    float kv = __bfloat162float(kt[r][i]);
    ks += kv;
#pragma unroll
    for (int jj = 0; jj < 16; ++jj)
      acc[jj] += kv * __bfloat162float(vt[r][j0 + jj]);
  }
  float* dst = part + ((size_t)blockIdx.x * 8 + h) * 4160;
#pragma unroll
  for (int jj = 0; jj < 16; ++jj) dst[i * 64 + j0 + jj] = acc[jj];
  if ((t & 3) == 0) dst[4096 + i] = ks;
}

__global__ void reduce_m(const float* __restrict__ part, float* __restrict__ Mfin) {
  int h = blockIdx.x, t = threadIdx.x;
  for (int idx = t; idx < 4160; idx += 256) {
    float s = 0.f;
    for (int c = 0; c < 32; ++c) s += part[((size_t)c * 8 + h) * 4160 + idx];
    Mfin[(size_t)h * 4160 + idx] = s;
  }
}

__global__ __launch_bounds__(256) void att_kernel(const __hip_bfloat16* __restrict__ QKV, int ld,
                                                  const float* __restrict__ Mfin,
                                                  __hip_bfloat16* __restrict__ att) {
  __shared__ float q[8][512];
  __shared__ float den[8][8];
  const int t = threadIdx.x;
  const int n0 = blockIdx.x * 8;
  for (int e = t; e < 8 * 512; e += 256) {
    int r = e >> 9, c = e & 511;
    q[r][c] = __bfloat162float(QKV[(size_t)(n0 + r) * ld + c]);
  }
  __syncthreads();
  if (t < 64) {
    int r = t >> 3, h = t & 7;
    const float* ks = Mfin + (size_t)h * 4160 + 4096;
    float s = 0.f;
    for (int i = 0; i < 64; ++i) s += q[r][h * 64 + i] * ks[i];
    den[r][h] = s * 0.125f + 1e-8f;
  }
  __syncthreads();
  for (int cc = 0; cc < 2; ++cc) {
    int j = t + cc * 256;
    int h = j >> 6, jh = j & 63;
    const float* Mc = Mfin + (size_t)h * 4160;
    float a0[8] = {};
    for (int i = 0; i < 64; ++i) {
      float m = Mc[i * 64 + jh];
#pragma unroll
      for (int r = 0; r < 8; ++r) a0[r] += q[r][h * 64 + i] * m;
    }
#pragma unroll
    for (int r = 0; r < 8; ++r)
      att[(size_t)(n0 + r) * 512 + j] = __float2bfloat16(a0[r] * 0.125f / den[r][h]);
  }
}

// ---------------------------------------------------------------------------
extern "C" void kernel_launch(void* const* d_in, const int* in_sizes, int n_in,
                              void* d_out, int out_size, void* d_ws, size_t ws_size,
                              hipStream_t stream) {
  const float* batch = (const float*)d_in[0];
  const float* w1[3] = {(const float*)d_in[1],  (const float*)d_in[7],  (const float*)d_in[13]};
  const float* b1[3] = {(const float*)d_in[2],  (const float*)d_in[8],  (const float*)d_in[14]};
  const float* w2[3] = {(const float*)d_in[3],  (const float*)d_in[9],  (const float*)d_in[15]};
  const float* b2[3] = {(const float*)d_in[4],  (const float*)d_in[10], (const float*)d_in[16]};
  const float* w3[3] = {(const float*)d_in[5],  (const float*)d_in[11], (const float*)d_in[17]};
  const float* b3[3] = {(const float*)d_in[6],  (const float*)d_in[12], (const float*)d_in[18]};
  const float* wow   = (const float*)d_in[19];
  const float* wob   = (const float*)d_in[20];

  char* ws = (char*)d_ws;
  __hip_bfloat16* XB  = (__hip_bfloat16*)(ws + OFF_XB);
  __hip_bfloat16* WT1 = (__hip_bfloat16*)(ws + OFF_WT1);
  __hip_bfloat16* WT2 = (__hip_bfloat16*)(ws + OFF_WT2);
  __hip_bfloat16* WT3 = (__hip_bfloat16*)(ws + OFF_WT3);
  __hip_bfloat16* WTO = (__hip_bfloat16*)(ws + OFF_WTO);
  float*          B1C = (float*)(ws + OFF_B1C);
  __hip_bfloat16* H1  = (__hip_bfloat16*)(ws + OFF_H1);
  __hip_bfloat16* H2  = (__hip_bfloat16*)(ws + OFF_H2);
  __hip_bfloat16* QKV = (__hip_bfloat16*)(ws + OFF_QKV);
  float*          MP  = (float*)(ws + OFF_MP);
  float*          MF  = (float*)(ws + OFF_MF);
  __hip_bfloat16* ATT = (__hip_bfloat16*)(ws + OFF_ATT);
  float*          OUT = (float*)d_out;

  // 1) input conversion / weight transposition (batched over z)
  conv_pad_batch<<<16384, 256, 0, stream>>>(batch, XB);
  concat3<<<24, 256, 0, stream>>>(b1[0], b1[1], b1[2], B1C);
  transpose_conv3<<<dim3(32, 64, 3), dim3(32, 8), 0, stream>>>(
      w1[0], w1[1], w1[2], WT1, (size_t)2048 * 1024, 1000, 2048, 1024);
  transpose_conv3<<<dim3(64, 32, 3), dim3(32, 8), 0, stream>>>(
      w2[0], w2[1], w2[2], WT2, (size_t)1024 * 2048, 2048, 1024, 2048);
  transpose_conv3<<<dim3(32, 16, 3), dim3(32, 8), 0, stream>>>(
      w3[0], w3[1], w3[2], WT3, (size_t)512 * 1024, 1024, 512, 1024);
  transpose_conv3<<<dim3(16, 32, 1), dim3(32, 8), 0, stream>>>(
      wow, wow, wow, WTO, 0, 512, 1000, 512);

  // 2) MLPs
  // G1 (merged q|k|v): [4096,1024] @ [1024,6144] -> H1 (relu)   [pipelined 256^2]
  gemm_p<<<dim3(24, 16, 1), 512, 0, stream>>>(XB, 1024, 0, WT1, 1024, 0,
                                              B1C, B1C, B1C, H1, 6144, 0, 1024, 1);
  // G2 z-batched: [4096,2048] @ [2048,1024] -> H2 (relu)        [pipelined 256^2]
  gemm_p<<<dim3(4, 16, 3), 512, 0, stream>>>(H1, 6144, 2048, WT2, 2048, (size_t)1024 * 2048,
                                             b2[0], b2[1], b2[2], H2, 3072, 1024, 2048, 1);
  // G3 z-batched: [4096,1024] @ [1024,512] -> QKV (q,k relu; v plain) [128^2]
  gemm_bt<<<dim3(4, 32, 3), 256, 0, stream>>>(H2, 3072, 1024, WT3, 1024, (size_t)512 * 1024,
                                              b3[0], b3[1], b3[2], QKV, 1536, 512,
                                              512, 1024, 3);

  // 3) attention (linear normalization => tiny per-head reductions)
  kv_outer<<<dim3(32, 8), 256, 0, stream>>>(QKV, 1536, MP);
  reduce_m<<<8, 256, 0, stream>>>(MP, MF);
  att_kernel<<<512, 256, 0, stream>>>(QKV, 1536, MF, ATT);

  // 4) output projection: [4096,512] @ [512,1000(+pad)] -> d_out fp32 [128^2]
  gemm_bt<<<dim3(8, 32, 1), 256, 0, stream>>>(ATT, 512, 0, WTO, 512, 0,
                                              wob, wob, wob, OUT, 1000, 0,
                                              1000, 512, 2);

  (void)in_sizes; (void)n_in; (void)out_size; (void)ws_size;
}

// Round 3
// 282.709 us; speedup vs baseline: 1.5838x; 1.0159x over previous
//
#include <hip/hip_runtime.h>
#include <hip/hip_bf16.h>

// ---------------------------------------------------------------------------
// MultiHeadAttention_21887153340754
// N=4096, IN=1000(pad 1024), H1=2048, H2=1024, EMB=512, HEADS=8, depth=64, OUT=1000
//
// Attention is LINEAR in scores (no softmax):
//   att = (qh @ M / sqrt(d)) / denom,  M = kh^T @ vh (per head, 64x64)
//   denom = (qh . ksum)/sqrt(d) + 1e-8
// => never materialize the 4096x4096 score matrix.
//
// Round 3: G1/G2 -> true 8-phase 256^2 template (m201 port): BK=64, half-tile
// (128 rows) staging 1/phase, quarter-split wave mapping, 2 barriers/phase,
// counted vmcnt(4/2) never 0 in steady state, setprio around 16-MFMA cluster.
// ---------------------------------------------------------------------------

typedef __attribute__((ext_vector_type(4))) float f32x4;
typedef __attribute__((ext_vector_type(8))) short bf16x8;

// ---- workspace layout (bytes) ---------------------------------------------
static constexpr size_t OFF_XB   = 0;                      // bf16 [4096][1024]
static constexpr size_t OFF_WT1  = OFF_XB   + 8388608;     // bf16 [6144][1024]
static constexpr size_t OFF_WT2  = OFF_WT1  + 12582912;    // bf16 [3][1024][2048]
static constexpr size_t OFF_WT3  = OFF_WT2  + 12582912;    // bf16 [3][512][1024]
static constexpr size_t OFF_WTO  = OFF_WT3  + 3145728;     // bf16 [1024][512]
static constexpr size_t OFF_B1C  = OFF_WTO  + 1048576;     // f32  [6144]
static constexpr size_t OFF_H1   = OFF_B1C  + 24576;       // bf16 [4096][6144]
static constexpr size_t OFF_H2   = OFF_H1   + 50331648;    // bf16 [4096][3072]
static constexpr size_t OFF_QKV  = OFF_H2   + 25165824;    // bf16 [4096][1536]
static constexpr size_t OFF_MP   = OFF_QKV  + 12582912;    // f32  [32][8][4160]
static constexpr size_t OFF_MF   = OFF_MP   + 4259840;     // f32  [8][4160]
static constexpr size_t OFF_ATT  = OFF_MF   + 133120;      // bf16 [4096][512]

__device__ __forceinline__ void gload16(const __hip_bfloat16* g, __hip_bfloat16* l) {
  __builtin_amdgcn_global_load_lds(
      (const __attribute__((address_space(1))) void*)g,
      (__attribute__((address_space(3))) void*)l, 16, 0, 0);
}

// ---- batch fp32 [4096][1000] -> bf16 [4096][1024] (zero pad) --------------
__global__ void conv_pad_batch(const float* __restrict__ in, __hip_bfloat16* __restrict__ out) {
  int idx = blockIdx.x * 256 + threadIdx.x;
  int r = idx >> 10, c = idx & 1023;
  float v = (c < 1000) ? in[(size_t)r * 1000 + c] : 0.f;
  out[idx] = __float2bfloat16(v);
}

__global__ void concat3(const float* __restrict__ a, const float* __restrict__ b,
                        const float* __restrict__ c, float* __restrict__ out) {
  int i = blockIdx.x * 256 + threadIdx.x;
  if (i < 6144) {
    const float* src = (i < 2048) ? a : ((i < 4096) ? b : c);
    out[i] = src[i & 2047];
  }
}

// ---- W [K][N] fp32 -> Wt [Npad][Kpad] bf16, batched over z ----------------
__global__ void transpose_conv3(const float* __restrict__ s0, const float* __restrict__ s1,
                                const float* __restrict__ s2, __hip_bfloat16* __restrict__ outb,
                                size_t ostride, int K, int N, int Kpad) {
  const float* in = (blockIdx.z == 0) ? s0 : ((blockIdx.z == 1) ? s1 : s2);
  __hip_bfloat16* out = outb + (size_t)blockIdx.z * ostride;
  __shared__ float tile[32][33];
  int kb = blockIdx.x * 32, nb = blockIdx.y * 32;
  int tx = threadIdx.x, ty = threadIdx.y;            // block (32,8)
  for (int i = ty; i < 32; i += 8) {
    int k = kb + i, n = nb + tx;
    tile[i][tx] = (k < K && n < N) ? in[(size_t)k * N + n] : 0.f;
  }
  __syncthreads();
  for (int i = ty; i < 32; i += 8) {
    int n = nb + i, kp = kb + tx;
    out[(size_t)n * Kpad + kp] = __float2bfloat16(tile[tx][i]);
  }
}

// ---------------------------------------------------------------------------
// gemm_p8: 256x256 tile, BK=64, 8 waves. Quarter-split wave mapping:
//   wave w: wm=w>>2, wn=w&3; output rows {mg*128 + wm*64 + i*16}, i=0..3,
//   mg in {0,1}; cols {ng*128 + wn*32 + jj*16}, jj in {0,1}, ng in {0,1}.
// LDS: sm[2 dbuf][4 halves: A0,A1,B0,B1][128x64 bf16] = 128 KiB.
// Swizzle (both sides): byte-slot s = colgroup ^ (row&7) within a row's 128B.
// Phases per K-tile T (cur=T&1; stages fill nxt=cur^1 with tile T+1):
//   ph0 (mg0,ng0): read A0(8),B0(4); stage A0'     -> 16 MFMA
//   ph1 (mg1,ng0): read A1(8);       stage A1'     -> 16 MFMA; vmcnt(4)
//   ph2 (mg1,ng1): read B1(4);       stage B0'     -> 16 MFMA
//   ph3 (mg0,ng1): read A0(8);       stage B1'     -> 16 MFMA; vmcnt(2)
// Ledger: vmcnt(2)@ph3 leaves only B1' in flight => A0',A1',B0' done before
// ph0/ph1 of T+1 read them. vmcnt(4)@ph1 leaves {A0'',A1''} => B1' done
// before ph2 reads it. Peeled last tile (no stages): vmcnt(0) at ph1.
// ---------------------------------------------------------------------------
__global__ __launch_bounds__(512, 2) void gemm_p8(
    const __hip_bfloat16* __restrict__ A, int lda, size_t Az,
    const __hip_bfloat16* __restrict__ B, int ldb, size_t Bz,
    const float* __restrict__ bias0, const float* __restrict__ bias1,
    const float* __restrict__ bias2,
    __hip_bfloat16* __restrict__ Cout, int ldc, size_t Cz,
    int NT, int relu) {
  __shared__ __hip_bfloat16 sm[2][4][8192];          // [buf][A0,A1,B0,B1][128*64]
  const int t = threadIdx.x;
  const int z = blockIdx.z;
  const int m0 = blockIdx.y * 256, n0 = blockIdx.x * 256;
  A += (size_t)z * Az;
  B += (size_t)z * Bz;
  const float* bias = (z == 0) ? bias0 : ((z == 1) ? bias1 : bias2);

  const int w = t >> 6, l = t & 63;
  const int wm = w >> 2, wn = w & 3;
  const int fr = l & 15, fq = l >> 4;

  // staging geometry: thread t covers half-tile bytes t*16 and t*16+8192;
  // linear LDS byte L -> row=L>>7, slot=(L>>4)&7, logical colgroup=slot^(row&7)
  const int row0 = t >> 3, row1 = row0 + 64;
  const int c0 = (t & 7) ^ (row0 & 7);
  const int c1 = (t & 7) ^ (row1 & 7);
  const __hip_bfloat16* gA0a = A + (size_t)(m0 + row0) * lda + c0 * 8;
  const __hip_bfloat16* gA0b = A + (size_t)(m0 + row1) * lda + c1 * 8;
  const __hip_bfloat16* gA1a = gA0a + (size_t)128 * lda;
  const __hip_bfloat16* gA1b = gA0b + (size_t)128 * lda;
  const __hip_bfloat16* gB0a = B + (size_t)(n0 + row0) * ldb + c0 * 8;
  const __hip_bfloat16* gB0b = B + (size_t)(n0 + row1) * ldb + c1 * 8;
  const __hip_bfloat16* gB1a = gB0a + (size_t)128 * ldb;
  const __hip_bfloat16* gB1b = gB0b + (size_t)128 * ldb;

  // ds_read offsets: frag row-in-half = wm*64+i*16+fr (A) / wn*32+jj*16+fr (B)
  // byte = row*128 + ((ks*4+fq)^(row&7))*16 ; row&7 == fr&7 here.
  const int baseA = (wm * 64 + fr) * 128;
  const int baseB = (wn * 32 + fr) * 128;
  const int xb0 = ((fq) ^ (fr & 7)) * 16;
  const int xb1 = ((4 + fq) ^ (fr & 7)) * 16;

  f32x4 acc[8][4] = {};
  bf16x8 af[4][2], bfv[2][2];

#define STG8(NXT, HALF, PA, PB, KT) do {                                       \
    gload16((PA) + (size_t)(KT) * 64, &sm[NXT][HALF][w * 512]);                \
    gload16((PB) + (size_t)(KT) * 64, &sm[NXT][HALF][w * 512 + 4096]);         \
  } while (0)

#define PH8(CUR, MG, NG, RDA, RDB, STG, WAITSTMT) do {                         \
    const char* a_ = (const char*)&sm[CUR][MG][0];                             \
    const char* b_ = (const char*)&sm[CUR][2 + (NG)][0];                       \
    if (RDA) {                                                                 \
      _Pragma("unroll") for (int i = 0; i < 4; ++i) {                          \
        af[i][0] = *(const bf16x8*)(a_ + baseA + i * 2048 + xb0);              \
        af[i][1] = *(const bf16x8*)(a_ + baseA + i * 2048 + xb1);              \
      }                                                                        \
    }                                                                          \
    if (RDB) {                                                                 \
      _Pragma("unroll") for (int j = 0; j < 2; ++j) {                          \
        bfv[j][0] = *(const bf16x8*)(b_ + baseB + j * 2048 + xb0);             \
        bfv[j][1] = *(const bf16x8*)(b_ + baseB + j * 2048 + xb1);             \
      }                                                                        \
    }                                                                          \
    STG;                                                                       \
    __builtin_amdgcn_s_barrier();                                              \
    asm volatile("s_waitcnt lgkmcnt(0)" ::: "memory");                         \
    __builtin_amdgcn_sched_barrier(0);                                         \
    __builtin_amdgcn_s_setprio(1);                                             \
    _Pragma("unroll") for (int ks = 0; ks < 2; ++ks)                           \
      _Pragma("unroll") for (int i = 0; i < 4; ++i)                            \
        _Pragma("unroll") for (int j = 0; j < 2; ++j)                          \
          acc[(MG) * 4 + i][(NG) * 2 + j] =                                    \
              __builtin_amdgcn_mfma_f32_16x16x32_bf16(                         \
                  af[i][ks], bfv[j][ks], acc[(MG) * 4 + i][(NG) * 2 + j],      \
                  0, 0, 0);                                                    \
    __builtin_amdgcn_s_setprio(0);                                             \
    WAITSTMT;                                                                  \
    __builtin_amdgcn_s_barrier();                                              \
  } while (0)

  // prologue: stage all 4 halves of tile 0 into buf 0, drain, barrier
  STG8(0, 0, gA0a, gA0b, 0);
  STG8(0, 1, gA1a, gA1b, 0);
  STG8(0, 2, gB0a, gB0b, 0);
  STG8(0, 3, gB1a, gB1b, 0);
  asm volatile("s_waitcnt vmcnt(0)" ::: "memory");
  __builtin_amdgcn_s_barrier();

  for (int T = 0; T < NT - 1; ++T) {
    const int cur = T & 1, nxt = cur ^ 1;
    const int kt = T + 1;
    PH8(cur, 0, 0, 1, 1, STG8(nxt, 0, gA0a, gA0b, kt), (void)0);
    PH8(cur, 1, 0, 1, 0, STG8(nxt, 1, gA1a, gA1b, kt),
        asm volatile("s_waitcnt vmcnt(4)" ::: "memory"));
    PH8(cur, 1, 1, 0, 1, STG8(nxt, 2, gB0a, gB0b, kt), (void)0);
    PH8(cur, 0, 1, 1, 0, STG8(nxt, 3, gB1a, gB1b, kt),
        asm volatile("s_waitcnt vmcnt(2)" ::: "memory"));
  }
  {
    const int cur = (NT - 1) & 1;
    PH8(cur, 0, 0, 1, 1, (void)0, (void)0);
    PH8(cur, 1, 0, 1, 0, (void)0,
        asm volatile("s_waitcnt vmcnt(0)" ::: "memory"));
    PH8(cur, 1, 1, 0, 1, (void)0, (void)0);
    PH8(cur, 0, 1, 1, 0, (void)0, (void)0);
  }
#undef PH8
#undef STG8

  // epilogue: quarter-split mapping
  __hip_bfloat16* C = Cout + (size_t)z * Cz;
  float bv[4];
#pragma unroll
  for (int nj = 0; nj < 4; ++nj) {
    const int col = n0 + (nj >> 1) * 128 + wn * 32 + (nj & 1) * 16 + fr;
    bv[nj] = bias[col];
  }
#pragma unroll
  for (int mi = 0; mi < 8; ++mi) {
    const int rowb = m0 + (mi >> 2) * 128 + wm * 64 + (mi & 3) * 16 + fq * 4;
#pragma unroll
    for (int nj = 0; nj < 4; ++nj) {
      const int col = n0 + (nj >> 1) * 128 + wn * 32 + (nj & 1) * 16 + fr;
#pragma unroll
      for (int rr = 0; rr < 4; ++rr) {
        float v = acc[mi][nj][rr] + bv[nj];
        if (relu) v = fmaxf(v, 0.f);
        C[(size_t)(rowb + rr) * ldc + col] = __float2bfloat16(v);
      }
    }
  }
}

// ---- generalized 128^2 m97-style GEMM (small shapes: G3, out-proj) --------
// epi: 0 = bf16, 1 = bf16+relu, 2 = f32 store guarded col<nlimit,
//      3 = bf16 + relu iff z<2
__global__ __launch_bounds__(256) void gemm_bt(
    const __hip_bfloat16* __restrict__ A, int lda, size_t Az,
    const __hip_bfloat16* __restrict__ B, int ldb, size_t Bz,
    const float* __restrict__ bias0, const float* __restrict__ bias1,
    const float* __restrict__ bias2,
    void* __restrict__ Cout, int ldc, size_t Cz,
    int nlimit, int K, int epi) {
  __shared__ __hip_bfloat16 As[128 * 32];
  __shared__ __hip_bfloat16 Bs[128 * 32];
  const int t = threadIdx.x;
  const int z = blockIdx.z;
  const int m0 = blockIdx.y * 128;
  const int n0 = blockIdx.x * 128;
  A += (size_t)z * Az;
  B += (size_t)z * Bz;
  const float* bias = (z == 0) ? bias0 : ((z == 1) ? bias1 : bias2);
  const int w = t >> 6, l = t & 63;
  const int wm = (w >> 1) * 64, wn = (w & 1) * 64;
  const int fr = l & 15, fq = l >> 4;
  const int sr = t >> 2, sc = (t & 3) * 8;

  f32x4 acc[4][4] = {};

  const __hip_bfloat16* ga = A + (size_t)(m0 + sr) * lda + sc;
  const __hip_bfloat16* gb = B + (size_t)(n0 + sr) * ldb + sc;
  __hip_bfloat16* la = As + w * 512;
  __hip_bfloat16* lb = Bs + w * 512;

  for (int k0 = 0; k0 < K; k0 += 32) {
    gload16(ga, la);
    gload16(ga + (size_t)64 * lda, la + 2048);
    gload16(gb, lb);
    gload16(gb + (size_t)64 * ldb, lb + 2048);
    ga += 32; gb += 32;
    __syncthreads();
    bf16x8 af[4], bfr[4];
#pragma unroll
    for (int i = 0; i < 4; ++i) {
      af[i]  = *reinterpret_cast<const bf16x8*>(&As[(wm + i * 16 + fr) * 32 + fq * 8]);
      bfr[i] = *reinterpret_cast<const bf16x8*>(&Bs[(wn + i * 16 + fr) * 32 + fq * 8]);
    }
#pragma unroll
    for (int i = 0; i < 4; ++i)
#pragma unroll
      for (int j = 0; j < 4; ++j)
        acc[i][j] = __builtin_amdgcn_mfma_f32_16x16x32_bf16(af[i], bfr[j], acc[i][j], 0, 0, 0);
    __syncthreads();
  }

  const bool dorelu = (epi == 1) || (epi == 3 && z < 2);
  float bv[4];
#pragma unroll
  for (int j = 0; j < 4; ++j) {
    int col = n0 + wn + j * 16 + fr;
    bv[j] = (col < nlimit) ? bias[col] : 0.f;
  }
#pragma unroll
  for (int i = 0; i < 4; ++i) {
#pragma unroll
    for (int j = 0; j < 4; ++j) {
      int col = n0 + wn + j * 16 + fr;
#pragma unroll
      for (int r = 0; r < 4; ++r) {
        int row = m0 + wm + i * 16 + fq * 4 + r;
        float v = acc[i][j][r] + bv[j];
        if (dorelu) v = fmaxf(v, 0.f);
        if (epi == 2) {
          if (col < nlimit)
            ((float*)Cout)[(size_t)row * ldc + col] = v;
        } else {
          ((__hip_bfloat16*)Cout + (size_t)z * Cz)[(size_t)row * ldc + col] = __float2bfloat16(v);
        }
      }
    }
  }
}

// ---- per-head partial M = kh^T vh (64x64) and ksum, over 128-row chunks ---
__global__ __launch_bounds__(256) void kv_outer(const __hip_bfloat16* __restrict__ QKV, int ld,
                                                float* __restrict__ part) {
  __shared__ __hip_bfloat16 kt[128][64];
  __shared__ __hip_bfloat16 vt[128][64];
  const int t = threadIdx.x;
  const int n0 = blockIdx.x * 128;
  const int h = blockIdx.y;
#pragma unroll
  for (int it = 0; it < 4; ++it) {
    int r = it * 32 + (t >> 3);
    int c = (t & 7) * 8;
    const __hip_bfloat16* kr = &QKV[(size_t)(n0 + r) * ld + 512 + h * 64 + c];
    const __hip_bfloat16* vr = &QKV[(size_t)(n0 + r) * ld + 1024 + h * 64 + c];
    *reinterpret_cast<bf16x8*>(&kt[r][c]) = *reinterpret_cast<const bf16x8*>(kr);
    *reinterpret_cast<bf16x8*>(&vt[r][c]) = *reinterpret_cast<const bf16x8*>(vr);
  }
  __syncthreads();
  const int i = t >> 2, j0 = (t & 3) << 4;
  float acc[16] = {};
  float ks = 0.f;
  for (int r = 0; r < 128; ++r) {
    float kv = __bfloat162float(kt[r][i]);
    ks += kv;
#pragma unroll
    for (int jj = 0; jj < 16; ++jj)
      acc[jj] += kv * __bfloat162float(vt[r][j0 + jj]);
  }
  float* dst = part + ((size_t)blockIdx.x * 8 + h) * 4160;
#pragma unroll
  for (int jj = 0; jj < 16; ++jj) dst[i * 64 + j0 + jj] = acc[jj];
  if ((t & 3) == 0) dst[4096 + i] = ks;
}

__global__ void reduce_m(const float* __restrict__ part, float* __restrict__ Mfin) {
  int h = blockIdx.x, t = threadIdx.x;
  for (int idx = t; idx < 4160; idx += 256) {
    float s = 0.f;
    for (int c = 0; c < 32; ++c) s += part[((size_t)c * 8 + h) * 4160 + idx];
    Mfin[(size_t)h * 4160 + idx] = s;
  }
}

__global__ __launch_bounds__(256) void att_kernel(const __hip_bfloat16* __restrict__ QKV, int ld,
                                                  const float* __restrict__ Mfin,
                                                  __hip_bfloat16* __restrict__ att) {
  __shared__ float q[8][512];
  __shared__ float den[8][8];
  const int t = threadIdx.x;
  const int n0 = blockIdx.x * 8;
  for (int e = t; e < 8 * 512; e += 256) {
    int r = e >> 9, c = e & 511;
    q[r][c] = __bfloat162float(QKV[(size_t)(n0 + r) * ld + c]);
  }
  __syncthreads();
  if (t < 64) {
    int r = t >> 3, h = t & 7;
    const float* ks = Mfin + (size_t)h * 4160 + 4096;
    float s = 0.f;
    for (int i = 0; i < 64; ++i) s += q[r][h * 64 + i] * ks[i];
    den[r][h] = s * 0.125f + 1e-8f;
  }
  __syncthreads();
  for (int cc = 0; cc < 2; ++cc) {
    int j = t + cc * 256;
    int h = j >> 6, jh = j & 63;
    const float* Mc = Mfin + (size_t)h * 4160;
    float a0[8] = {};
    for (int i = 0; i < 64; ++i) {
      float m = Mc[i * 64 + jh];
#pragma unroll
      for (int r = 0; r < 8; ++r) a0[r] += q[r][h * 64 + i] * m;
    }
#pragma unroll
    for (int r = 0; r < 8; ++r)
      att[(size_t)(n0 + r) * 512 + j] = __float2bfloat16(a0[r] * 0.125f / den[r][h]);
  }
}

// ---------------------------------------------------------------------------
extern "C" void kernel_launch(void* const* d_in, const int* in_sizes, int n_in,
                              void* d_out, int out_size, void* d_ws, size_t ws_size,
                              hipStream_t stream) {
  const float* batch = (const float*)d_in[0];
  const float* w1[3] = {(const float*)d_in[1],  (const float*)d_in[7],  (const float*)d_in[13]};
  const float* b1[3] = {(const float*)d_in[2],  (const float*)d_in[8],  (const float*)d_in[14]};
  const float* w2[3] = {(const float*)d_in[3],  (const float*)d_in[9],  (const float*)d_in[15]};
  const float* b2[3] = {(const float*)d_in[4],  (const float*)d_in[10], (const float*)d_in[16]};
  const float* w3[3] = {(const float*)d_in[5],  (const float*)d_in[11], (const float*)d_in[17]};
  const float* b3[3] = {(const float*)d_in[6],  (const float*)d_in[12], (const float*)d_in[18]};
  const float* wow   = (const float*)d_in[19];
  const float* wob   = (const float*)d_in[20];

  char* ws = (char*)d_ws;
  __hip_bfloat16* XB  = (__hip_bfloat16*)(ws + OFF_XB);
  __hip_bfloat16* WT1 = (__hip_bfloat16*)(ws + OFF_WT1);
  __hip_bfloat16* WT2 = (__hip_bfloat16*)(ws + OFF_WT2);
  __hip_bfloat16* WT3 = (__hip_bfloat16*)(ws + OFF_WT3);
  __hip_bfloat16* WTO = (__hip_bfloat16*)(ws + OFF_WTO);
  float*          B1C = (float*)(ws + OFF_B1C);
  __hip_bfloat16* H1  = (__hip_bfloat16*)(ws + OFF_H1);
  __hip_bfloat16* H2  = (__hip_bfloat16*)(ws + OFF_H2);
  __hip_bfloat16* QKV = (__hip_bfloat16*)(ws + OFF_QKV);
  float*          MP  = (float*)(ws + OFF_MP);
  float*          MF  = (float*)(ws + OFF_MF);
  __hip_bfloat16* ATT = (__hip_bfloat16*)(ws + OFF_ATT);
  float*          OUT = (float*)d_out;

  // 1) input conversion / weight transposition (batched over z)
  conv_pad_batch<<<16384, 256, 0, stream>>>(batch, XB);
  concat3<<<24, 256, 0, stream>>>(b1[0], b1[1], b1[2], B1C);
  transpose_conv3<<<dim3(32, 64, 3), dim3(32, 8), 0, stream>>>(
      w1[0], w1[1], w1[2], WT1, (size_t)2048 * 1024, 1000, 2048, 1024);
  transpose_conv3<<<dim3(64, 32, 3), dim3(32, 8), 0, stream>>>(
      w2[0], w2[1], w2[2], WT2, (size_t)1024 * 2048, 2048, 1024, 2048);
  transpose_conv3<<<dim3(32, 16, 3), dim3(32, 8), 0, stream>>>(
      w3[0], w3[1], w3[2], WT3, (size_t)512 * 1024, 1024, 512, 1024);
  transpose_conv3<<<dim3(16, 32, 1), dim3(32, 8), 0, stream>>>(
      wow, wow, wow, WTO, 0, 512, 1000, 512);

  // 2) MLPs
  // G1 (merged q|k|v): [4096,1024] @ [1024,6144] -> H1 (relu)  [8-phase 256^2]
  gemm_p8<<<dim3(24, 16, 1), 512, 0, stream>>>(XB, 1024, 0, WT1, 1024, 0,
                                               B1C, B1C, B1C, H1, 6144, 0, 16, 1);
  // G2 z-batched: [4096,2048] @ [2048,1024] -> H2 (relu)       [8-phase 256^2]
  gemm_p8<<<dim3(4, 16, 3), 512, 0, stream>>>(H1, 6144, 2048, WT2, 2048, (size_t)1024 * 2048,
                                              b2[0], b2[1], b2[2], H2, 3072, 1024, 32, 1);
  // G3 z-batched: [4096,1024] @ [1024,512] -> QKV (q,k relu; v plain) [128^2]
  gemm_bt<<<dim3(4, 32, 3), 256, 0, stream>>>(H2, 3072, 1024, WT3, 1024, (size_t)512 * 1024,
                                              b3[0], b3[1], b3[2], QKV, 1536, 512,
                                              512, 1024, 3);

  // 3) attention (linear normalization => tiny per-head reductions)
  kv_outer<<<dim3(32, 8), 256, 0, stream>>>(QKV, 1536, MP);
  reduce_m<<<8, 256, 0, stream>>>(MP, MF);
  att_kernel<<<512, 256, 0, stream>>>(QKV, 1536, MF, ATT);

  // 4) output projection: [4096,512] @ [512,1000(+pad)] -> d_out fp32 [128^2]
  gemm_bt<<<dim3(8, 32, 1), 256, 0, stream>>>(ATT, 512, 0, WTO, 512, 0,
                                              wob, wob, wob, OUT, 1000, 0,
                                              1000, 512, 2);

  (void)in_sizes; (void)n_in; (void)out_size; (void)ws_size;
}